// Round 7
// baseline (479.891 us; speedup 1.0000x reference)
//
#include <hip/hip_runtime.h>
#include <math.h>

// Problem constants: B=8, CIN=3, COUT=16, H=W=384
#define BQ   8
#define CIN  3
#define COUT 16
#define HW   (384 * 384)            // 147456
#define NPIX (BQ * HW)              // 1,179,648 pixels
#define NELT 18874368.0f            // NPIX * COUT
#define MAX_ITERS 16

#define TPB       256
#define NBLK      768               // 3 blocks/CU * 256 CU; co-resident via launch_bounds(256,3)
#define NTHREADS  (NBLK * TPB)      // 196,608
#define PPT       6                 // 196,608 * 6 == NPIX exactly -> 96 VGPRs of state

#define NLEAF        64
#define BLK_PER_LEAF (NBLK / NLEAF) // 12

typedef float vfloat16 __attribute__((ext_vector_type(16)));

struct __align__(64) PadCnt { int cnt; int pad[15]; };  // one cache line each

struct Ctl {
    PadCnt leaf[NLEAF];
    PadCnt root;
    PadCnt sense;
    float  partials[MAX_ITERS + 1][NBLK];
};

__global__ void k_init(Ctl* c) {
    int t = threadIdx.x;
    if (t < NLEAF) c->leaf[t].cnt = 0;
    if (t == 0) { c->root.cnt = 0; c->sense.cnt = 0; }
}

// tanh(x) = 1 - 2/(exp(2x)+1): v_exp_f32 + v_rcp_f32, ~1e-7 abs err.
__device__ __forceinline__ float tanh_fast(float x) {
    float e = __expf(2.0f * x);
    return fmaf(-2.0f, __builtin_amdgcn_rcpf(e + 1.0f), 1.0f);
}

__device__ __forceinline__ float block_reduce_add(float v) {
    #pragma unroll
    for (int off = 32; off > 0; off >>= 1)
        v += __shfl_down(v, off, 64);
    __shared__ float red[TPB / 64];
    int lane = threadIdx.x & 63;
    int wid  = threadIdx.x >> 6;
    if (lane == 0) red[wid] = v;
    __syncthreads();
    float r = 0.f;
    if (threadIdx.x == 0) {
        #pragma unroll
        for (int i = 0; i < TPB / 64; ++i) r += red[i];
    }
    return r;
}

// Two-level sense-reversing grid barrier: leaf fan-in 12, root fan-in 64.
__device__ __forceinline__ void grid_barrier(Ctl* c, int* sense_sh) {
    __syncthreads();
    if (threadIdx.x == 0) {
        int next = *sense_sh ^ 1;
        int lf = blockIdx.x & (NLEAF - 1);
        int p = __hip_atomic_fetch_add(&c->leaf[lf].cnt, 1, __ATOMIC_ACQ_REL,
                                       __HIP_MEMORY_SCOPE_AGENT);
        if (p == BLK_PER_LEAF - 1) {
            __hip_atomic_store(&c->leaf[lf].cnt, 0, __ATOMIC_RELAXED,
                               __HIP_MEMORY_SCOPE_AGENT);
            int q = __hip_atomic_fetch_add(&c->root.cnt, 1, __ATOMIC_ACQ_REL,
                                           __HIP_MEMORY_SCOPE_AGENT);
            if (q == NLEAF - 1) {
                __hip_atomic_store(&c->root.cnt, 0, __ATOMIC_RELAXED,
                                   __HIP_MEMORY_SCOPE_AGENT);
                __hip_atomic_store(&c->sense.cnt, next, __ATOMIC_RELEASE,
                                   __HIP_MEMORY_SCOPE_AGENT);
            }
        }
        while (__hip_atomic_load(&c->sense.cnt, __ATOMIC_ACQUIRE,
                                 __HIP_MEMORY_SCOPE_AGENT) != next)
            __builtin_amdgcn_s_sleep(4);
        *sense_sh = next;
    }
    __syncthreads();
}

// Deterministic grid sum: wave 0 sums all NBLK partials in a fixed order
// (identical in every block -> bitwise-identical -> uniform decision).
__device__ __forceinline__ float grid_sum(const float* part, float* bc) {
    int lane = threadIdx.x & 63, wid = threadIdx.x >> 6;
    if (wid == 0) {
        float s = 0.f;
        #pragma unroll
        for (int i = 0; i < NBLK / 64; ++i)
            s += __hip_atomic_load(&part[i * 64 + lane], __ATOMIC_RELAXED,
                                   __HIP_MEMORY_SCOPE_AGENT);
        #pragma unroll
        for (int off = 32; off > 0; off >>= 1)
            s += __shfl_down(s, off, 64);
        if (lane == 0) *bc = s;
    }
    __syncthreads();
    return *bc;
}

// ---- per-pixel macros over NAMED ext-vectors (no arrays -> guaranteed SROA) ----

#define PRE_PIXEL(vk, kk)                                                \
    { int p = tid + (kk) * NTHREADS; int b = p / HW; int hw = p - b * HW;\
      const float* xb = x + (size_t)b * (CIN * HW) + hw;                 \
      float x0 = xb[0], x1 = xb[HW], x2 = xb[2 * HW];                    \
      _Pragma("unroll")                                                  \
      for (int o = 0; o < COUT; ++o) {                                   \
          float a = bp[o];                                               \
          a = fmaf(wp[o * CIN + 0], x0, a);                              \
          a = fmaf(wp[o * CIN + 1], x1, a);                              \
          a = fmaf(wp[o * CIN + 2], x2, a);                              \
          vk[o] = a; s += fabsf(a);                                      \
      } }

#define STEP_PIXEL(vk)                                                   \
    { float tt[COUT];                                                    \
      _Pragma("unroll")                                                  \
      for (int o = 0; o < COUT; ++o) {                                   \
          float a = bs[o];                                               \
          _Pragma("unroll")                                              \
          for (int c = 0; c < COUT; ++c)                                 \
              a = fmaf(ws[o * COUT + c], vk[c], a);                      \
          tt[o] = tanh_fast(a);                                          \
      }                                                                  \
      _Pragma("unroll")                                                  \
      for (int o = 0; o < COUT; ++o) {                                   \
          float a = bl[o];                                               \
          _Pragma("unroll")                                              \
          for (int c = 0; c < COUT; ++c)                                 \
              a = fmaf(wl[o * COUT + c], tt[c], a);                      \
          a *= 10.f;                                                     \
          vk[o] = a; s += fabsf(a);                                      \
      } }

#define FIN_PIXEL(vk, kk)                                                \
    { int p = tid + (kk) * NTHREADS; int b = p / HW; int hw = p - b * HW;\
      float* ob = out + (size_t)b * (COUT * HW) + hw;                    \
      _Pragma("unroll")                                                  \
      for (int o = 0; o < COUT; ++o) {                                   \
          float a = bs[o];                                               \
          _Pragma("unroll")                                              \
          for (int c = 0; c < COUT; ++c)                                 \
              a = fmaf(ws[o * COUT + c], vk[c], a);                      \
          ob[(size_t)o * HW] = a;                                        \
      } }

// 3 blocks/CU: VGPR cap 168; state 96 + working ~50 fits in ARCH VGPRs
// (no AGPR demotion/shuttling), 12 waves/CU for latency hiding.
__global__ __launch_bounds__(TPB, 3) void k_persist(
        const float* __restrict__ x,
        const float* __restrict__ wp, const float* __restrict__ bp,
        const float* __restrict__ wl, const float* __restrict__ bl,
        const float* __restrict__ ws, const float* __restrict__ bs,
        float* __restrict__ out, Ctl* __restrict__ ctl) {
    __shared__ int sense_sh;
    __shared__ float bcast;
    const int t = threadIdx.x;
    if (t == 0) sense_sh = 0;
    __syncthreads();

    const int tid = blockIdx.x * TPB + t;

    // State: 6 named 16-wide vectors = 96 registers.
    vfloat16 v0, v1, v2, v3, v4, v5;

    // ---- pre conv + |v| partial
    float s = 0.f;
    PRE_PIXEL(v0, 0) PRE_PIXEL(v1, 1) PRE_PIXEL(v2, 2)
    PRE_PIXEL(v3, 3) PRE_PIXEL(v4, 4) PRE_PIXEL(v5, 5)
    {
        float r = block_reduce_add(s);
        if (t == 0)
            __hip_atomic_store(&ctl->partials[0][blockIdx.x], r,
                               __ATOMIC_RELAXED, __HIP_MEMORY_SCOPE_AGENT);
    }
    grid_barrier(ctl, &sense_sh);

    // ---- while (mean|v| < 3): v = 10*(wl @ tanh(ws @ v + bs) + bl)
    int it = 0;
    while (it < MAX_ITERS) {
        float total = grid_sum(ctl->partials[it], &bcast);
        if (total >= 3.0f * NELT) break;      // uniform across all blocks

        s = 0.f;
        STEP_PIXEL(v0) STEP_PIXEL(v1) STEP_PIXEL(v2)
        STEP_PIXEL(v3) STEP_PIXEL(v4) STEP_PIXEL(v5)
        ++it;
        float r = block_reduce_add(s);
        if (t == 0)
            __hip_atomic_store(&ctl->partials[it][blockIdx.x], r,
                               __ATOMIC_RELAXED, __HIP_MEMORY_SCOPE_AGENT);
        grid_barrier(ctl, &sense_sh);
    }

    // ---- final conv
    FIN_PIXEL(v0, 0) FIN_PIXEL(v1, 1) FIN_PIXEL(v2, 2)
    FIN_PIXEL(v3, 3) FIN_PIXEL(v4, 4) FIN_PIXEL(v5, 5)
}

extern "C" void kernel_launch(void* const* d_in, const int* in_sizes, int n_in,
                              void* d_out, int out_size, void* d_ws, size_t ws_size,
                              hipStream_t stream) {
    // dict order: x, w_pre, b_pre, w_loop, b_loop, w_shared, b_shared
    const float* x  = (const float*)d_in[0];
    const float* wp = (const float*)d_in[1];
    const float* bp = (const float*)d_in[2];
    const float* wl = (const float*)d_in[3];
    const float* bl = (const float*)d_in[4];
    const float* ws = (const float*)d_in[5];
    const float* bs = (const float*)d_in[6];
    float* out = (float*)d_out;
    Ctl*   ctl = (Ctl*)d_ws;

    k_init<<<1, 64, 0, stream>>>(ctl);
    k_persist<<<NBLK, TPB, 0, stream>>>(x, wp, bp, wl, bl, ws, bs, out, ctl);
}